// Round 12
// baseline (316231.079 us; speedup 1.0000x reference)
//
#include <hip/hip_runtime.h>

#define BC 64            // batch chunk
#define NB (BC * 32)     // neighbor rows per chunk

__device__ __forceinline__ float fs(float f) {
    return (f == f && fabsf(f) < 1e30f) ? f : 0.f;
}
__device__ __forceinline__ float fin(float v) {  // output guard: non-finite -> 555 sentinel
    return (v == v && fabsf(v) < 1e30f) ? v : 555.0f;
}
__device__ __forceinline__ float gelu_f(float x) {
    return 0.5f * x * (1.0f + erff(x * 0.70710678118654752440f));
}

__global__ void fill_kernel(float* __restrict__ out, int n, float val) {
    int i = blockIdx.x * 256 + threadIdx.x;
    if (i < n) out[i] = val;
}

// nbr row (30) + sdiff row (12), one thread per (b,k)
__global__ void k_prep(const float* __restrict__ qobs, const float* __restrict__ qmask,
                       const float* __restrict__ rshift, const int* __restrict__ rsmask,
                       const int* __restrict__ qcode, const int* __restrict__ rcodes,
                       const float* __restrict__ rdist, const float* __restrict__ rc_table,
                       const float* __restrict__ E_res,
                       float* __restrict__ nbr, float* __restrict__ sdiff)
{
    int gk = blockIdx.x * 256 + threadIdx.x;
    if (gk >= NB) return;
    int b = gk >> 5;
    int qc = qcode[b], rc = rcodes[gk];
    int qi = min(max(qc, 0), 20), ri = min(max(rc, 0), 20);
    float dist = fs(rdist[gk]);
    float same = (rc == qc) ? 1.f : 0.f;
    float* nr = nbr + (size_t)gk * 30;
    float* sd = sdiff + (size_t)gk * 12;
    for (int s = 0; s < 6; s++) {
        float rs = fs(rshift[gk * 6 + s]);
        bool m = rsmask[gk * 6 + s] != 0;
        float rq = rc_table[qi * 6 + s];
        float rr = rc_table[ri * 6 + s];
        bool rcv = (rq == rq) && (rr == rr) && fabsf(rq) < 1e30f && fabsf(rr) < 1e30f;
        float sh = (m && rcv) ? (rq + rs - rr) : rs;
        nr[s] = sh;
        nr[6 + s] = m ? 1.f : 0.f;
        float qm = fs(qmask[b * 6 + s]);
        sd[s] = (fs(qobs[b * 6 + s]) - sh) * qm;
        sd[6 + s] = qm;
    }
    for (int j = 0; j < 16; j++) nr[12 + j] = fs(E_res[ri * 16 + j]);
    nr[28] = dist;
    nr[29] = same;
}

// trust/global stats, one thread per b, fully serial
__global__ void k_stats(const float* __restrict__ nbr, const int* __restrict__ rvalid,
                        float* __restrict__ pst, float* __restrict__ gst,
                        float* __restrict__ anyv)
{
    int b = blockIdx.x * 64 + threadIdx.x;
    if (b >= BC) return;
    float svf = 0.f, sdm = 0.f, mdm = -1e30f, ssm = 0.f;
    for (int k = 0; k < 32; k++) {
        const float* nr = nbr + (size_t)(b * 32 + k) * 30;
        float vf = (rvalid[b * 32 + k] != 0) ? 1.f : 0.f;
        float dm = vf * nr[28];
        svf += vf; sdm += dm; mdm = fmaxf(mdm, dm); ssm += vf * nr[29];
    }
    for (int s = 0; s < 6; s++) {
        float cnt = 0.f, msum = 0.f, mdist = 0.f, mst = 0.f;
        for (int k = 0; k < 32; k++) {
            const float* nr = nbr + (size_t)(b * 32 + k) * 30;
            float vf = (rvalid[b * 32 + k] != 0) ? 1.f : 0.f;
            float vm = vf * nr[6 + s];
            cnt += vm; msum += nr[s] * vm; mdist += nr[28] * vm; mst += nr[29] * vm;
        }
        float inv = 1.f / (cnt + 1e-8f);
        float mean = msum * inv;
        float var = 0.f;
        for (int k = 0; k < 32; k++) {
            const float* nr = nbr + (size_t)(b * 32 + k) * 30;
            float vf = (rvalid[b * 32 + k] != 0) ? 1.f : 0.f;
            float vm = vf * nr[6 + s];
            float dv = nr[s] - mean;
            var += dv * dv * vm;
        }
        var *= inv;
        float* p = pst + (size_t)b * 24 + s * 4;
        p[0] = cnt * (1.f / 32.f);
        p[1] = fminf(fmaxf(log1pf(var), 0.f), 5.f) * 0.2f;
        p[2] = mdist * inv;
        p[3] = mst * inv;
    }
    float* g = gst + (size_t)b * 4;
    g[0] = sdm / (svf + 1e-8f);
    g[1] = mdm;
    g[2] = svf * (1.f / 32.f);
    g[3] = ssm * (1.f / 32.f);
    anyv[b] = (svf > 0.f) ? 1.f : 0.f;
}

template <int ACT>
__global__ void k_gemm(const float* __restrict__ A, int lda,
                       const float* __restrict__ B, const float* __restrict__ bias,
                       float* __restrict__ C, int M, int N, int K)
{
    int id = blockIdx.x * 256 + threadIdx.x;
    if (id >= M * N) return;
    int m = id / N, n = id - m * N;
    float acc = bias ? fs(bias[n]) : 0.f;
    const float* Ap = A + (size_t)m * lda;
    for (int k = 0; k < K; k++) acc += Ap[k] * fs(B[(size_t)k * N + n]);
    C[id] = (ACT == 1) ? gelu_f(acc) : acc;
}

__global__ void k_qp(const float* __restrict__ Qh, const float* __restrict__ Wak,
                     float* __restrict__ Qp)
{
    int id = blockIdx.x * 256 + threadIdx.x;
    if (id >= BC * 2304) return;
    int b = id / 2304, c = id - b * 2304, h = c / 384, j = c - h * 384;
    float acc = 0.f;
    for (int d = 0; d < 64; d++)
        acc += Qh[(size_t)b * 384 + h * 64 + d] * fs(Wak[(size_t)j * 384 + h * 64 + d]);
    Qp[id] = acc;
}

__global__ void k_qkb(const float* __restrict__ Qh, const float* __restrict__ bak,
                      float* __restrict__ qkb)
{
    int id = blockIdx.x * 256 + threadIdx.x;
    if (id >= BC * 6) return;
    int b = id / 6, h = id - b * 6;
    float acc = 0.f;
    for (int d = 0; d < 64; d++)
        acc += Qh[(size_t)b * 384 + h * 64 + d] * fs(bak[h * 64 + d]);
    qkb[id] = acc;
}

// FUSED attention span: scores -> masked softmax -> vmix -> W_av projection.
__global__ void k_fusedattn(const float* __restrict__ kv, const float* __restrict__ Qp,
                            const float* __restrict__ qkb, const float* __restrict__ bias_s,
                            const int* __restrict__ rvalid, const float* __restrict__ anyv,
                            const float* __restrict__ Wav, const float* __restrict__ bav,
                            float* __restrict__ attn)
{
    int id = blockIdx.x * 256 + threadIdx.x;
    if (id >= BC * 6) return;
    int b = id / 6, h = id - b * 6;
    const float* qpp = Qp + (size_t)b * 2304 + (size_t)h * 384;
    float qk = qkb[b * 6 + h];
    float av0 = anyv[b];
    float sc[32];
    float mx = -1e30f;
    for (int k = 0; k < 32; k++) {
        const float* kvp = kv + (size_t)(b * 32 + k) * 384;
        float s = 0.f;
        for (int j = 0; j < 384; j++) s += kvp[j] * qpp[j];
        s = (s + qk) * 0.125f + bias_s[(size_t)(b * 32 + k) * 6 + h];
        bool ve = (rvalid[b * 32 + k] != 0) || (av0 == 0.f && k == 0);
        sc[k] = ve ? s : -10000.f;
        mx = fmaxf(mx, sc[k]);
    }
    float sum = 0.f;
    for (int k = 0; k < 32; k++) { sc[k] = expf(sc[k] - mx); sum += sc[k]; }
    float inv = 1.f / sum;
    for (int k = 0; k < 32; k++) sc[k] *= inv;
    float vm[384];
    for (int j = 0; j < 384; j++) vm[j] = 0.f;
    for (int k = 0; k < 32; k++) {
        const float* kvp = kv + (size_t)(b * 32 + k) * 384;
        float wk = sc[k];
        for (int j = 0; j < 384; j++) vm[j] += wk * kvp[j];
    }
    for (int d = 0; d < 64; d++) {
        int c = h * 64 + d;
        float acc = fs(bav[c]);
        for (int j = 0; j < 384; j++) acc += vm[j] * fs(Wav[(size_t)j * 384 + c]);
        attn[(size_t)b * 384 + c] = acc;
    }
}

__global__ void k_ctxout(const float* __restrict__ ctx, const float* __restrict__ anyv,
                         const float* __restrict__ fctx, float* __restrict__ out)
{
    int id = blockIdx.x * 256 + threadIdx.x;
    if (id >= BC * 384) return;
    int b = id / 384, c = id - b * 384;
    float v = (anyv[b] > 0.f) ? ctx[id] : fs(fctx[c]);
    out[id] = fin(v);
}

__global__ void k_xtc(const float* __restrict__ tq, const int* __restrict__ qcode,
                      const float* __restrict__ Etr, const float* __restrict__ gst,
                      float* __restrict__ X)
{
    int id = blockIdx.x * 256 + threadIdx.x;
    if (id >= BC * 420) return;
    int b = id / 420, c = id - b * 420;
    float v;
    if (c < 384) v = tq[(size_t)b * 384 + c];
    else if (c < 416) v = fs(Etr[min(max(qcode[b], 0), 20) * 32 + (c - 384)]);
    else v = gst[(size_t)b * 4 + (c - 416)];
    X[id] = v;
}

__global__ void k_transfer(const float* __restrict__ nbr, const int* __restrict__ rsmask,
                           const int* __restrict__ rvalid, const float* __restrict__ swb,
                           const float* __restrict__ anyv, const float* __restrict__ sscale,
                           const float* __restrict__ fshift, float* __restrict__ out)
{
    int id = blockIdx.x * 256 + threadIdx.x;
    if (id >= BC * 6) return;
    int b = id / 6, s = id - b * 6;
    float res;
    if (anyv[b] <= 0.f) {
        res = fs(fshift[s]);
    } else {
        float wb = swb[b * 6 + s] * 0.1f;
        float mx = -1e30f;
        for (int k = 0; k < 32; k++) {
            int gk = b * 32 + k;
            bool m = (rvalid[gk] != 0) && (rsmask[gk * 6 + s] != 0);
            float wv = m ? (nbr[(size_t)gk * 30 + 28] + nbr[(size_t)gk * 30 + 29] * 0.5f + wb)
                         : -10000.f;
            mx = fmaxf(mx, wv);
        }
        float num = 0.f, den = 0.f;
        for (int k = 0; k < 32; k++) {
            int gk = b * 32 + k;
            bool m = (rvalid[gk] != 0) && (rsmask[gk * 6 + s] != 0);
            float wv = m ? (nbr[(size_t)gk * 30 + 28] + nbr[(size_t)gk * 30 + 29] * 0.5f + wb)
                         : -10000.f;
            float e = expf(wv - mx);
            num += e * nbr[(size_t)gk * 30 + s];
            den += e;
        }
        res = (num / den) * fs(sscale[s]);
    }
    out[id] = fin(res);
}

__global__ void k_trust(const float* __restrict__ tcp, const float* __restrict__ pst,
                        const float* __restrict__ Wtp1, const float* __restrict__ Wtp2,
                        const float* __restrict__ btp2, float* __restrict__ out)
{
    int id = blockIdx.x * 256 + threadIdx.x;
    if (id >= BC * 6) return;
    int b = id / 6, s = id - b * 6;
    const float* ps = pst + (size_t)b * 24 + s * 4;
    float acc = 0.f;
    for (int j = 0; j < 192; j++) {
        float pre = tcp[(size_t)b * 192 + j];
        pre += ps[0] * fs(Wtp1[(size_t)384 * 192 + j]);
        pre += ps[1] * fs(Wtp1[(size_t)385 * 192 + j]);
        pre += ps[2] * fs(Wtp1[(size_t)386 * 192 + j]);
        pre += ps[3] * fs(Wtp1[(size_t)387 * 192 + j]);
        acc += gelu_f(pre) * fs(Wtp2[j]);
    }
    float t = 1.f / (1.f + expf(-(acc + fs(btp2[0]))));
    out[id] = fin(t);
}

#define L1(total) <<<((total) + 255) / 256, 256, 0, stream>>>

extern "C" void kernel_launch(void* const* d_in, const int* in_sizes, int n_in,
                              void* d_out, int out_size, void* d_ws, size_t ws_size,
                              hipStream_t stream)
{
    float* out = (float*)d_out;   // reference outputs are float32 -> d_out is float*

    // input-order verification (confirmed passing in R11; kept as guard)
    static const int EXP[45] = {
        2097152, 4096, 24576, 24576, 786432, 786432, 131072, 131072, 131072, 126,
        196608, 384, 336, 11520, 384, 147456, 384, 147456, 384, 147456, 384,
        2304, 192, 1152, 6, 147456, 384, 147456, 384, 147456, 384, 2304, 6,
        672, 196608, 384, 161280, 384, 74496, 192, 192, 1, 6, 6, 384
    };
    if (n_in != 45) {
        fill_kernel L1(out_size)(out, out_size, 580.0f);
        return;
    }
    for (int i = 0; i < 45; i++) {
        if (in_sizes[i] != EXP[i]) {
            fill_kernel L1(out_size)(out, out_size, 600.0f + 4.0f * i);
            return;
        }
    }

    const float* i_qe    = (const float*)d_in[0];
    const int*   i_qcode = (const int*)d_in[1];
    const float* i_qobs  = (const float*)d_in[2];
    const float* i_qmask = (const float*)d_in[3];
    const float* i_rshift= (const float*)d_in[4];
    const int*   i_rsmask= (const int*)d_in[5];
    const int*   i_rcodes= (const int*)d_in[6];
    const float* i_rdist = (const float*)d_in[7];
    const int*   i_rvalid= (const int*)d_in[8];
    const float* i_rc    = (const float*)d_in[9];
    const float* i_Wqp   = (const float*)d_in[10];
    const float* i_bqp   = (const float*)d_in[11];
    const float* i_Eres  = (const float*)d_in[12];
    const float* i_Wnp   = (const float*)d_in[13];
    const float* i_bnp   = (const float*)d_in[14];
    const float* i_Waq   = (const float*)d_in[15];
    const float* i_baq   = (const float*)d_in[16];
    const float* i_Wak   = (const float*)d_in[17];
    const float* i_bak   = (const float*)d_in[18];
    const float* i_Wav   = (const float*)d_in[19];
    const float* i_bav   = (const float*)d_in[20];
    const float* i_Wss1  = (const float*)d_in[21];
    const float* i_bss1  = (const float*)d_in[22];
    const float* i_Wss2  = (const float*)d_in[23];
    const float* i_bss2  = (const float*)d_in[24];
    const float* i_Wcp1  = (const float*)d_in[25];
    const float* i_bcp1  = (const float*)d_in[26];
    const float* i_Wcp2  = (const float*)d_in[27];
    const float* i_bcp2  = (const float*)d_in[28];
    const float* i_Wsw1  = (const float*)d_in[29];
    const float* i_bsw1  = (const float*)d_in[30];
    const float* i_Wsw2  = (const float*)d_in[31];
    const float* i_bsw2  = (const float*)d_in[32];
    const float* i_Etr   = (const float*)d_in[33];
    const float* i_Wtq   = (const float*)d_in[34];
    const float* i_btq   = (const float*)d_in[35];
    const float* i_Wtc   = (const float*)d_in[36];
    const float* i_btc   = (const float*)d_in[37];
    const float* i_Wtp1  = (const float*)d_in[38];
    const float* i_btp1  = (const float*)d_in[39];
    const float* i_Wtp2  = (const float*)d_in[40];
    const float* i_btp2  = (const float*)d_in[41];
    const float* i_sscale= (const float*)d_in[42];
    const float* i_fshift= (const float*)d_in[43];
    const float* i_fctx  = (const float*)d_in[44];

    char* wsb = (char*)d_ws;
    size_t off = 0;
    auto alloc = [&](size_t nfloats) -> float* {
        float* p = (float*)(wsb + off);
        off = (off + nfloats * 4 + 255) & ~(size_t)255;
        return p;
    };
    float* nbr   = alloc((size_t)NB * 30);
    float* sdiff = alloc((size_t)NB * 12);
    float* kv    = alloc((size_t)NB * 384);
    float* hid   = alloc((size_t)NB * 192);
    float* bias_s= alloc((size_t)NB * 6);
    float* qf    = alloc((size_t)BC * 384);
    float* tqf   = alloc((size_t)BC * 384);
    float* Qhf   = alloc((size_t)BC * 384);
    float* attnf = alloc((size_t)BC * 384);
    float* h1f   = alloc((size_t)BC * 384);
    float* s1f   = alloc((size_t)BC * 384);
    float* ctxf  = alloc((size_t)BC * 384);
    float* tcf   = alloc((size_t)BC * 384);
    float* tcpf  = alloc((size_t)BC * 192);
    float* Xf    = alloc((size_t)BC * 420);
    float* Qpf   = alloc((size_t)BC * 2304);
    float* swbf  = alloc((size_t)BC * 6);
    float* qkbf  = alloc((size_t)BC * 6);
    float* pstf  = alloc((size_t)BC * 24);
    float* gstf  = alloc((size_t)BC * 4);
    float* anyf  = alloc((size_t)BC);

    if (off > ws_size) {
        fill_kernel L1(out_size)(out, out_size, 1000.0f);
        return;
    }

    for (int c = 0; c < 4096 / BC; c++) {
        const size_t B0 = (size_t)c * BC;
        k_prep L1(NB)(i_qobs + B0 * 6, i_qmask + B0 * 6, i_rshift + B0 * 192,
                      i_rsmask + B0 * 192, i_qcode + B0, i_rcodes + B0 * 32,
                      i_rdist + B0 * 32, i_rc, i_Eres, nbr, sdiff);
        k_stats L1(BC)(nbr, i_rvalid + B0 * 32, pstf, gstf, anyf);
        k_gemm<1> L1(NB * 384)(nbr, 30, i_Wnp, i_bnp, kv, NB, 384, 30);
        k_gemm<1> L1(NB * 192)(sdiff, 12, i_Wss1, i_bss1, hid, NB, 192, 12);
        k_gemm<0> L1(NB * 6)(hid, 192, i_Wss2, i_bss2, bias_s, NB, 6, 192);
        k_gemm<1> L1(BC * 384)(i_qe + B0 * 512, 512, i_Wqp, i_bqp, qf, BC, 384, 512);
        k_gemm<1> L1(BC * 384)(i_qe + B0 * 512, 512, i_Wtq, i_btq, tqf, BC, 384, 512);
        k_gemm<0> L1(BC * 384)(qf, 384, i_Waq, i_baq, Qhf, BC, 384, 384);
        k_qp L1(BC * 2304)(Qhf, i_Wak, Qpf);
        k_qkb L1(BC * 6)(Qhf, i_bak, qkbf);
        k_fusedattn L1(BC * 6)(kv, Qpf, qkbf, bias_s, i_rvalid + B0 * 32, anyf,
                               i_Wav, i_bav, attnf);
        k_gemm<1> L1(BC * 384)(attnf, 384, i_Wcp1, i_bcp1, h1f, BC, 384, 384);
        k_gemm<0> L1(BC * 384)(h1f, 384, i_Wcp2, i_bcp2, ctxf, BC, 384, 384);
        k_gemm<1> L1(BC * 384)(attnf, 384, i_Wsw1, i_bsw1, s1f, BC, 384, 384);
        k_gemm<0> L1(BC * 6)(s1f, 384, i_Wsw2, i_bsw2, swbf, BC, 6, 384);
        k_ctxout L1(BC * 384)(ctxf, anyf, i_fctx, out + B0 * 384);
        k_xtc L1(BC * 420)(tqf, i_qcode + B0, i_Etr, gstf, Xf);
        k_gemm<1> L1(BC * 384)(Xf, 420, i_Wtc, i_btc, tcf, BC, 384, 420);
        k_gemm<0> L1(BC * 192)(tcf, 384, i_Wtp1, i_btp1, tcpf, BC, 192, 384);
        k_trust L1(BC * 6)(tcpf, pstf, i_Wtp1, i_Wtp2, i_btp2,
                           out + (size_t)4096 * 390 + B0 * 6);
        k_transfer L1(BC * 6)(nbr, i_rsmask + B0 * 192, i_rvalid + B0 * 32, swbf, anyf,
                              i_sscale, i_fshift, out + (size_t)4096 * 384 + B0 * 6);
    }
}

// Round 13
// 5201.119 us; speedup vs baseline: 60.8006x; 60.8006x over previous
//
#include <hip/hip_runtime.h>

__device__ __forceinline__ float fs(float f) {
    return (f == f && fabsf(f) < 1e30f) ? f : 0.f;
}
__device__ __forceinline__ float fin(float v) {  // output guard: non-finite -> 555 sentinel
    return (v == v && fabsf(v) < 1e30f) ? v : 555.0f;
}
__device__ __forceinline__ float gelu_f(float x) {
    return 0.5f * x * (1.0f + erff(x * 0.70710678118654752440f));
}

__global__ void fill_kernel(float* __restrict__ out, int n, float val) {
    int i = blockIdx.x * 256 + threadIdx.x;
    if (i < n) out[i] = val;
}

// nbr row (30) + sdiff row (12), one thread per (b,k); NBc = BC*32
__global__ void k_prep(const float* __restrict__ qobs, const float* __restrict__ qmask,
                       const float* __restrict__ rshift, const int* __restrict__ rsmask,
                       const int* __restrict__ qcode, const int* __restrict__ rcodes,
                       const float* __restrict__ rdist, const float* __restrict__ rc_table,
                       const float* __restrict__ E_res,
                       float* __restrict__ nbr, float* __restrict__ sdiff, int NBc)
{
    int gk = blockIdx.x * 256 + threadIdx.x;
    if (gk >= NBc) return;
    int b = gk >> 5;
    int qc = qcode[b], rc = rcodes[gk];
    int qi = min(max(qc, 0), 20), ri = min(max(rc, 0), 20);
    float dist = fs(rdist[gk]);
    float same = (rc == qc) ? 1.f : 0.f;
    float* nr = nbr + (size_t)gk * 30;
    float* sd = sdiff + (size_t)gk * 12;
    for (int s = 0; s < 6; s++) {
        float rs = fs(rshift[gk * 6 + s]);
        bool m = rsmask[gk * 6 + s] != 0;
        float rq = rc_table[qi * 6 + s];
        float rr = rc_table[ri * 6 + s];
        bool rcv = (rq == rq) && (rr == rr) && fabsf(rq) < 1e30f && fabsf(rr) < 1e30f;
        float sh = (m && rcv) ? (rq + rs - rr) : rs;
        nr[s] = sh;
        nr[6 + s] = m ? 1.f : 0.f;
        float qm = fs(qmask[b * 6 + s]);
        sd[s] = (fs(qobs[b * 6 + s]) - sh) * qm;
        sd[6 + s] = qm;
    }
    for (int j = 0; j < 16; j++) nr[12 + j] = fs(E_res[ri * 16 + j]);
    nr[28] = dist;
    nr[29] = same;
}

// trust/global stats, one thread per b
__global__ void k_stats(const float* __restrict__ nbr, const int* __restrict__ rvalid,
                        float* __restrict__ pst, float* __restrict__ gst,
                        float* __restrict__ anyv, int BCc)
{
    int b = blockIdx.x * 256 + threadIdx.x;
    if (b >= BCc) return;
    float svf = 0.f, sdm = 0.f, mdm = -1e30f, ssm = 0.f;
    for (int k = 0; k < 32; k++) {
        const float* nr = nbr + (size_t)(b * 32 + k) * 30;
        float vf = (rvalid[b * 32 + k] != 0) ? 1.f : 0.f;
        float dm = vf * nr[28];
        svf += vf; sdm += dm; mdm = fmaxf(mdm, dm); ssm += vf * nr[29];
    }
    for (int s = 0; s < 6; s++) {
        float cnt = 0.f, msum = 0.f, mdist = 0.f, mst = 0.f;
        for (int k = 0; k < 32; k++) {
            const float* nr = nbr + (size_t)(b * 32 + k) * 30;
            float vf = (rvalid[b * 32 + k] != 0) ? 1.f : 0.f;
            float vm = vf * nr[6 + s];
            cnt += vm; msum += nr[s] * vm; mdist += nr[28] * vm; mst += nr[29] * vm;
        }
        float inv = 1.f / (cnt + 1e-8f);
        float mean = msum * inv;
        float var = 0.f;
        for (int k = 0; k < 32; k++) {
            const float* nr = nbr + (size_t)(b * 32 + k) * 30;
            float vf = (rvalid[b * 32 + k] != 0) ? 1.f : 0.f;
            float vm = vf * nr[6 + s];
            float dv = nr[s] - mean;
            var += dv * dv * vm;
        }
        var *= inv;
        float* p = pst + (size_t)b * 24 + s * 4;
        p[0] = cnt * (1.f / 32.f);
        p[1] = fminf(fmaxf(log1pf(var), 0.f), 5.f) * 0.2f;
        p[2] = mdist * inv;
        p[3] = mst * inv;
    }
    float* g = gst + (size_t)b * 4;
    g[0] = sdm / (svf + 1e-8f);
    g[1] = mdm;
    g[2] = svf * (1.f / 32.f);
    g[3] = ssm * (1.f / 32.f);
    anyv[b] = (svf > 0.f) ? 1.f : 0.f;
}

template <int ACT>
__global__ void k_gemm(const float* __restrict__ A, int lda,
                       const float* __restrict__ B, const float* __restrict__ bias,
                       float* __restrict__ C, int M, int N, int K)
{
    int id = blockIdx.x * 256 + threadIdx.x;
    if (id >= M * N) return;
    int m = id / N, n = id - m * N;
    float acc = bias ? fs(bias[n]) : 0.f;
    const float* Ap = A + (size_t)m * lda;
    for (int k = 0; k < K; k++) acc += Ap[k] * fs(B[(size_t)k * N + n]);
    C[id] = (ACT == 1) ? gelu_f(acc) : acc;
}

__global__ void k_qp(const float* __restrict__ Qh, const float* __restrict__ Wak,
                     float* __restrict__ Qp, int BCc)
{
    int id = blockIdx.x * 256 + threadIdx.x;
    if (id >= BCc * 2304) return;
    int b = id / 2304, c = id - b * 2304, h = c / 384, j = c - h * 384;
    float acc = 0.f;
    for (int d = 0; d < 64; d++)
        acc += Qh[(size_t)b * 384 + h * 64 + d] * fs(Wak[(size_t)j * 384 + h * 64 + d]);
    Qp[id] = acc;
}

__global__ void k_qkb(const float* __restrict__ Qh, const float* __restrict__ bak,
                      float* __restrict__ qkb, int BCc)
{
    int id = blockIdx.x * 256 + threadIdx.x;
    if (id >= BCc * 6) return;
    int b = id / 6, h = id - b * 6;
    float acc = 0.f;
    for (int d = 0; d < 64; d++)
        acc += Qh[(size_t)b * 384 + h * 64 + d] * fs(bak[h * 64 + d]);
    qkb[id] = acc;
}

// block-parallel attention: one block per b, 384 threads; kv+vmix staged in LDS.
// Same math / summation order as the verified serial k_fusedattn.
__global__ __launch_bounds__(384) void k_attnblk(
    const float* __restrict__ kv, const float* __restrict__ Qp,
    const float* __restrict__ qkb, const float* __restrict__ bias_s,
    const int* __restrict__ rvalid, const float* __restrict__ anyv,
    const float* __restrict__ Wav, const float* __restrict__ bav,
    float* __restrict__ attn)
{
    __shared__ float kvs[32 * 384];   // 48 KB
    __shared__ float vms[6 * 384];    // 9 KB
    __shared__ float wsx[192];        // softmax weights
    const int b = blockIdx.x;
    const int t = threadIdx.x;
    // stage kv[b] (coalesced)
    for (int i = 0; i < 32; i++) kvs[i * 384 + t] = kv[(size_t)b * 12288 + i * 384 + t];
    __syncthreads();
    // scores: 192 (h,k) pairs
    if (t < 192) {
        int h = t >> 5, k = t & 31;
        const float* qpp = Qp + (size_t)b * 2304 + (size_t)h * 384;
        float s = 0.f;
        for (int j = 0; j < 384; j++) s += kvs[k * 384 + j] * qpp[j];
        s = (s + qkb[b * 6 + h]) * 0.125f + bias_s[(size_t)(b * 32 + k) * 6 + h];
        bool ve = (rvalid[b * 32 + k] != 0) || (anyv[b] == 0.f && k == 0);
        wsx[h * 32 + k] = ve ? s : -10000.f;
    }
    __syncthreads();
    if (t < 6) {
        float mx = -1e30f;
        for (int k = 0; k < 32; k++) mx = fmaxf(mx, wsx[t * 32 + k]);
        float sum = 0.f;
        for (int k = 0; k < 32; k++) { float e = expf(wsx[t * 32 + k] - mx); wsx[t * 32 + k] = e; sum += e; }
        float inv = 1.f / sum;
        for (int k = 0; k < 32; k++) wsx[t * 32 + k] *= inv;
    }
    __syncthreads();
    // vmix: 2304 outputs, 6 per thread
    for (int i = 0; i < 6; i++) {
        int idx = i * 384 + t;
        int h = idx / 384, j = idx - h * 384;
        float acc = 0.f;
        for (int k = 0; k < 32; k++) acc += wsx[h * 32 + k] * kvs[k * 384 + j];
        vms[idx] = acc;
    }
    __syncthreads();
    // projection: c = t
    {
        int c = t, h = c >> 6;
        float acc = fs(bav[c]);
        const float* vp = vms + h * 384;
        for (int j = 0; j < 384; j++) acc += vp[j] * fs(Wav[(size_t)j * 384 + c]);
        attn[(size_t)b * 384 + c] = acc;
    }
}

__global__ void k_ctxout(const float* __restrict__ ctx, const float* __restrict__ anyv,
                         const float* __restrict__ fctx, float* __restrict__ out, int BCc)
{
    int id = blockIdx.x * 256 + threadIdx.x;
    if (id >= BCc * 384) return;
    int b = id / 384, c = id - b * 384;
    float v = (anyv[b] > 0.f) ? ctx[id] : fs(fctx[c]);
    out[id] = fin(v);
}

__global__ void k_xtc(const float* __restrict__ tq, const int* __restrict__ qcode,
                      const float* __restrict__ Etr, const float* __restrict__ gst,
                      float* __restrict__ X, int BCc)
{
    int id = blockIdx.x * 256 + threadIdx.x;
    if (id >= BCc * 420) return;
    int b = id / 420, c = id - b * 420;
    float v;
    if (c < 384) v = tq[(size_t)b * 384 + c];
    else if (c < 416) v = fs(Etr[min(max(qcode[b], 0), 20) * 32 + (c - 384)]);
    else v = gst[(size_t)b * 4 + (c - 416)];
    X[id] = v;
}

__global__ void k_transfer(const float* __restrict__ nbr, const int* __restrict__ rsmask,
                           const int* __restrict__ rvalid, const float* __restrict__ swb,
                           const float* __restrict__ anyv, const float* __restrict__ sscale,
                           const float* __restrict__ fshift, float* __restrict__ out, int BCc)
{
    int id = blockIdx.x * 256 + threadIdx.x;
    if (id >= BCc * 6) return;
    int b = id / 6, s = id - b * 6;
    float res;
    if (anyv[b] <= 0.f) {
        res = fs(fshift[s]);
    } else {
        float wb = swb[b * 6 + s] * 0.1f;
        float mx = -1e30f;
        for (int k = 0; k < 32; k++) {
            int gk = b * 32 + k;
            bool m = (rvalid[gk] != 0) && (rsmask[gk * 6 + s] != 0);
            float wv = m ? (nbr[(size_t)gk * 30 + 28] + nbr[(size_t)gk * 30 + 29] * 0.5f + wb)
                         : -10000.f;
            mx = fmaxf(mx, wv);
        }
        float num = 0.f, den = 0.f;
        for (int k = 0; k < 32; k++) {
            int gk = b * 32 + k;
            bool m = (rvalid[gk] != 0) && (rsmask[gk * 6 + s] != 0);
            float wv = m ? (nbr[(size_t)gk * 30 + 28] + nbr[(size_t)gk * 30 + 29] * 0.5f + wb)
                         : -10000.f;
            float e = expf(wv - mx);
            num += e * nbr[(size_t)gk * 30 + s];
            den += e;
        }
        res = (num / den) * fs(sscale[s]);
    }
    out[id] = fin(res);
}

__global__ void k_trust(const float* __restrict__ tcp, const float* __restrict__ pst,
                        const float* __restrict__ Wtp1, const float* __restrict__ Wtp2,
                        const float* __restrict__ btp2, float* __restrict__ out, int BCc)
{
    int id = blockIdx.x * 256 + threadIdx.x;
    if (id >= BCc * 6) return;
    int b = id / 6, s = id - b * 6;
    const float* ps = pst + (size_t)b * 24 + s * 4;
    float acc = 0.f;
    for (int j = 0; j < 192; j++) {
        float pre = tcp[(size_t)b * 192 + j];
        pre += ps[0] * fs(Wtp1[(size_t)384 * 192 + j]);
        pre += ps[1] * fs(Wtp1[(size_t)385 * 192 + j]);
        pre += ps[2] * fs(Wtp1[(size_t)386 * 192 + j]);
        pre += ps[3] * fs(Wtp1[(size_t)387 * 192 + j]);
        acc += gelu_f(pre) * fs(Wtp2[j]);
    }
    float t = 1.f / (1.f + expf(-(acc + fs(btp2[0]))));
    out[id] = fin(t);
}

#define L1(total) <<<((total) + 255) / 256, 256, 0, stream>>>

extern "C" void kernel_launch(void* const* d_in, const int* in_sizes, int n_in,
                              void* d_out, int out_size, void* d_ws, size_t ws_size,
                              hipStream_t stream)
{
    float* out = (float*)d_out;

    static const int EXP[45] = {
        2097152, 4096, 24576, 24576, 786432, 786432, 131072, 131072, 131072, 126,
        196608, 384, 336, 11520, 384, 147456, 384, 147456, 384, 147456, 384,
        2304, 192, 1152, 6, 147456, 384, 147456, 384, 147456, 384, 2304, 6,
        672, 196608, 384, 161280, 384, 74496, 192, 192, 1, 6, 6, 384
    };
    if (n_in != 45) {
        fill_kernel L1(out_size)(out, out_size, 580.0f);
        return;
    }
    for (int i = 0; i < 45; i++) {
        if (in_sizes[i] != EXP[i]) {
            fill_kernel L1(out_size)(out, out_size, 600.0f + 4.0f * i);
            return;
        }
    }

    const float* i_qe    = (const float*)d_in[0];
    const int*   i_qcode = (const int*)d_in[1];
    const float* i_qobs  = (const float*)d_in[2];
    const float* i_qmask = (const float*)d_in[3];
    const float* i_rshift= (const float*)d_in[4];
    const int*   i_rsmask= (const int*)d_in[5];
    const int*   i_rcodes= (const int*)d_in[6];
    const float* i_rdist = (const float*)d_in[7];
    const int*   i_rvalid= (const int*)d_in[8];
    const float* i_rc    = (const float*)d_in[9];
    const float* i_Wqp   = (const float*)d_in[10];
    const float* i_bqp   = (const float*)d_in[11];
    const float* i_Eres  = (const float*)d_in[12];
    const float* i_Wnp   = (const float*)d_in[13];
    const float* i_bnp   = (const float*)d_in[14];
    const float* i_Waq   = (const float*)d_in[15];
    const float* i_baq   = (const float*)d_in[16];
    const float* i_Wak   = (const float*)d_in[17];
    const float* i_bak   = (const float*)d_in[18];
    const float* i_Wav   = (const float*)d_in[19];
    const float* i_bav   = (const float*)d_in[20];
    const float* i_Wss1  = (const float*)d_in[21];
    const float* i_bss1  = (const float*)d_in[22];
    const float* i_Wss2  = (const float*)d_in[23];
    const float* i_bss2  = (const float*)d_in[24];
    const float* i_Wcp1  = (const float*)d_in[25];
    const float* i_bcp1  = (const float*)d_in[26];
    const float* i_Wcp2  = (const float*)d_in[27];
    const float* i_bcp2  = (const float*)d_in[28];
    const float* i_Wsw1  = (const float*)d_in[29];
    const float* i_bsw1  = (const float*)d_in[30];
    const float* i_Wsw2  = (const float*)d_in[31];
    const float* i_bsw2  = (const float*)d_in[32];
    const float* i_Etr   = (const float*)d_in[33];
    const float* i_Wtq   = (const float*)d_in[34];
    const float* i_btq   = (const float*)d_in[35];
    const float* i_Wtc   = (const float*)d_in[36];
    const float* i_btc   = (const float*)d_in[37];
    const float* i_Wtp1  = (const float*)d_in[38];
    const float* i_btp1  = (const float*)d_in[39];
    const float* i_Wtp2  = (const float*)d_in[40];
    const float* i_btp2  = (const float*)d_in[41];
    const float* i_sscale= (const float*)d_in[42];
    const float* i_fshift= (const float*)d_in[43];
    const float* i_fctx  = (const float*)d_in[44];

    // ws-adaptive chunk size: largest BC whose layout fits (same alloc arithmetic)
    auto layoutBytes = [](int bc) -> size_t {
        size_t nb = (size_t)bc * 32, off = 0;
        auto a = [&](size_t nf) { off = (off + nf * 4 + 255) & ~(size_t)255; };
        a(nb * 30); a(nb * 12); a(nb * 384); a(nb * 192); a(nb * 6);
        a((size_t)bc * 384); a((size_t)bc * 384); a((size_t)bc * 384); a((size_t)bc * 384);
        a((size_t)bc * 384); a((size_t)bc * 384); a((size_t)bc * 384); a((size_t)bc * 384);
        a((size_t)bc * 192); a((size_t)bc * 420); a((size_t)bc * 2304);
        a((size_t)bc * 6); a((size_t)bc * 6); a((size_t)bc * 24); a((size_t)bc * 4); a(bc);
        return off;
    };
    const int cand[7] = {4096, 2048, 1024, 512, 256, 128, 64};
    int BCc = 64;
    for (int i = 0; i < 7; i++) {
        if (layoutBytes(cand[i]) <= ws_size) { BCc = cand[i]; break; }
    }
    const int NBc = BCc * 32;

    char* wsb = (char*)d_ws;
    size_t off = 0;
    auto alloc = [&](size_t nfloats) -> float* {
        float* p = (float*)(wsb + off);
        off = (off + nfloats * 4 + 255) & ~(size_t)255;
        return p;
    };
    float* nbr   = alloc((size_t)NBc * 30);
    float* sdiff = alloc((size_t)NBc * 12);
    float* kv    = alloc((size_t)NBc * 384);
    float* hid   = alloc((size_t)NBc * 192);
    float* bias_s= alloc((size_t)NBc * 6);
    float* qf    = alloc((size_t)BCc * 384);
    float* tqf   = alloc((size_t)BCc * 384);
    float* Qhf   = alloc((size_t)BCc * 384);
    float* attnf = alloc((size_t)BCc * 384);
    float* h1f   = alloc((size_t)BCc * 384);
    float* s1f   = alloc((size_t)BCc * 384);
    float* ctxf  = alloc((size_t)BCc * 384);
    float* tcf   = alloc((size_t)BCc * 384);
    float* tcpf  = alloc((size_t)BCc * 192);
    float* Xf    = alloc((size_t)BCc * 420);
    float* Qpf   = alloc((size_t)BCc * 2304);
    float* swbf  = alloc((size_t)BCc * 6);
    float* qkbf  = alloc((size_t)BCc * 6);
    float* pstf  = alloc((size_t)BCc * 24);
    float* gstf  = alloc((size_t)BCc * 4);
    float* anyf  = alloc((size_t)BCc);

    if (off > ws_size) {
        fill_kernel L1(out_size)(out, out_size, 1000.0f);
        return;
    }

    for (int c = 0; c < 4096 / BCc; c++) {
        const size_t B0 = (size_t)c * BCc;
        k_prep L1(NBc)(i_qobs + B0 * 6, i_qmask + B0 * 6, i_rshift + B0 * 192,
                       i_rsmask + B0 * 192, i_qcode + B0, i_rcodes + B0 * 32,
                       i_rdist + B0 * 32, i_rc, i_Eres, nbr, sdiff, NBc);
        k_stats L1(BCc)(nbr, i_rvalid + B0 * 32, pstf, gstf, anyf, BCc);
        k_gemm<1> L1(NBc * 384)(nbr, 30, i_Wnp, i_bnp, kv, NBc, 384, 30);
        k_gemm<1> L1(NBc * 192)(sdiff, 12, i_Wss1, i_bss1, hid, NBc, 192, 12);
        k_gemm<0> L1(NBc * 6)(hid, 192, i_Wss2, i_bss2, bias_s, NBc, 6, 192);
        k_gemm<1> L1(BCc * 384)(i_qe + B0 * 512, 512, i_Wqp, i_bqp, qf, BCc, 384, 512);
        k_gemm<1> L1(BCc * 384)(i_qe + B0 * 512, 512, i_Wtq, i_btq, tqf, BCc, 384, 512);
        k_gemm<0> L1(BCc * 384)(qf, 384, i_Waq, i_baq, Qhf, BCc, 384, 384);
        k_qp L1(BCc * 2304)(Qhf, i_Wak, Qpf, BCc);
        k_qkb L1(BCc * 6)(Qhf, i_bak, qkbf, BCc);
        k_attnblk<<<BCc, 384, 0, stream>>>(kv, Qpf, qkbf, bias_s, i_rvalid + B0 * 32,
                                           anyf, i_Wav, i_bav, attnf);
        k_gemm<1> L1(BCc * 384)(attnf, 384, i_Wcp1, i_bcp1, h1f, BCc, 384, 384);
        k_gemm<0> L1(BCc * 384)(h1f, 384, i_Wcp2, i_bcp2, ctxf, BCc, 384, 384);
        k_gemm<1> L1(BCc * 384)(attnf, 384, i_Wsw1, i_bsw1, s1f, BCc, 384, 384);
        k_gemm<0> L1(BCc * 6)(s1f, 384, i_Wsw2, i_bsw2, swbf, BCc, 6, 384);
        k_ctxout L1(BCc * 384)(ctxf, anyf, i_fctx, out + B0 * 384, BCc);
        k_xtc L1(BCc * 420)(tqf, i_qcode + B0, i_Etr, gstf, Xf, BCc);
        k_gemm<1> L1(BCc * 384)(Xf, 420, i_Wtc, i_btc, tcf, BCc, 384, 420);
        k_gemm<0> L1(BCc * 192)(tcf, 384, i_Wtp1, i_btp1, tcpf, BCc, 192, 384);
        k_trust L1(BCc * 6)(tcpf, pstf, i_Wtp1, i_Wtp2, i_btp2,
                            out + (size_t)4096 * 390 + B0 * 6, BCc);
        k_transfer L1(BCc * 6)(nbr, i_rsmask + B0 * 192, i_rvalid + B0 * 32, swbf, anyf,
                               i_sscale, i_fshift, out + (size_t)4096 * 384 + B0 * 6, BCc);
    }
}

// Round 14
// 1768.549 us; speedup vs baseline: 178.8082x; 2.9409x over previous
//
#include <hip/hip_runtime.h>

typedef unsigned short u16;
typedef __attribute__((ext_vector_type(8))) short bf16x8;
typedef __attribute__((ext_vector_type(4))) float f32x4;

__device__ __forceinline__ float fs(float f) {
    return (f == f && fabsf(f) < 1e30f) ? f : 0.f;
}
__device__ __forceinline__ float fin(float v) {
    return (v == v && fabsf(v) < 1e30f) ? v : 555.0f;
}
__device__ __forceinline__ u16 f2b(float f) {
    union { float f; unsigned int i; } w; w.f = f;
    unsigned int r = w.i + 0x7FFFu + ((w.i >> 16) & 1u);
    return (u16)(r >> 16);
}
__device__ __forceinline__ float gelu_f(float x) {
    return 0.5f * x * (1.0f + erff(x * 0.70710678118654752440f));
}

__global__ void fill_kernel(float* __restrict__ out, int n, float val) {
    int i = blockIdx.x * 256 + threadIdx.x;
    if (i < n) out[i] = val;
}

// nbr row (30) + sdiff row (12), one thread per (b,k)
__global__ void k_prep(const float* __restrict__ qobs, const float* __restrict__ qmask,
                       const float* __restrict__ rshift, const int* __restrict__ rsmask,
                       const int* __restrict__ qcode, const int* __restrict__ rcodes,
                       const float* __restrict__ rdist, const float* __restrict__ rc_table,
                       const float* __restrict__ E_res,
                       float* __restrict__ nbr, float* __restrict__ sdiff, int NBc)
{
    int gk = blockIdx.x * 256 + threadIdx.x;
    if (gk >= NBc) return;
    int b = gk >> 5;
    int qc = qcode[b], rc = rcodes[gk];
    int qi = min(max(qc, 0), 20), ri = min(max(rc, 0), 20);
    float dist = fs(rdist[gk]);
    float same = (rc == qc) ? 1.f : 0.f;
    float* nr = nbr + (size_t)gk * 30;
    float* sd = sdiff + (size_t)gk * 12;
    for (int s = 0; s < 6; s++) {
        float rs = fs(rshift[gk * 6 + s]);
        bool m = rsmask[gk * 6 + s] != 0;
        float rq = rc_table[qi * 6 + s];
        float rr = rc_table[ri * 6 + s];
        bool rcv = (rq == rq) && (rr == rr) && fabsf(rq) < 1e30f && fabsf(rr) < 1e30f;
        float sh = (m && rcv) ? (rq + rs - rr) : rs;
        nr[s] = sh;
        nr[6 + s] = m ? 1.f : 0.f;
        float qm = fs(qmask[b * 6 + s]);
        sd[s] = (fs(qobs[b * 6 + s]) - sh) * qm;
        sd[6 + s] = qm;
    }
    for (int j = 0; j < 16; j++) nr[12 + j] = fs(E_res[ri * 16 + j]);
    nr[28] = dist;
    nr[29] = same;
}

__global__ void k_stats(const float* __restrict__ nbr, const int* __restrict__ rvalid,
                        float* __restrict__ pst, float* __restrict__ gst,
                        float* __restrict__ anyv, int BCc)
{
    int b = blockIdx.x * 256 + threadIdx.x;
    if (b >= BCc) return;
    float svf = 0.f, sdm = 0.f, mdm = -1e30f, ssm = 0.f;
    for (int k = 0; k < 32; k++) {
        const float* nr = nbr + (size_t)(b * 32 + k) * 30;
        float vf = (rvalid[b * 32 + k] != 0) ? 1.f : 0.f;
        float dm = vf * nr[28];
        svf += vf; sdm += dm; mdm = fmaxf(mdm, dm); ssm += vf * nr[29];
    }
    for (int s = 0; s < 6; s++) {
        float cnt = 0.f, msum = 0.f, mdist = 0.f, mst = 0.f;
        for (int k = 0; k < 32; k++) {
            const float* nr = nbr + (size_t)(b * 32 + k) * 30;
            float vf = (rvalid[b * 32 + k] != 0) ? 1.f : 0.f;
            float vm = vf * nr[6 + s];
            cnt += vm; msum += nr[s] * vm; mdist += nr[28] * vm; mst += nr[29] * vm;
        }
        float inv = 1.f / (cnt + 1e-8f);
        float mean = msum * inv;
        float var = 0.f;
        for (int k = 0; k < 32; k++) {
            const float* nr = nbr + (size_t)(b * 32 + k) * 30;
            float vf = (rvalid[b * 32 + k] != 0) ? 1.f : 0.f;
            float vm = vf * nr[6 + s];
            float dv = nr[s] - mean;
            var += dv * dv * vm;
        }
        var *= inv;
        float* p = pst + (size_t)b * 24 + s * 4;
        p[0] = cnt * (1.f / 32.f);
        p[1] = fminf(fmaxf(log1pf(var), 0.f), 5.f) * 0.2f;
        p[2] = mdist * inv;
        p[3] = mst * inv;
    }
    float* g = gst + (size_t)b * 4;
    g[0] = sdm / (svf + 1e-8f);
    g[1] = mdm;
    g[2] = svf * (1.f / 32.f);
    g[3] = ssm * (1.f / 32.f);
    anyv[b] = (svf > 0.f) ? 1.f : 0.f;
}

// scalar GEMM (kept for small-N cases): C = act(A@B + bias)
template <int ACT>
__global__ void k_gemm(const float* __restrict__ A, int lda,
                       const float* __restrict__ B, const float* __restrict__ bias,
                       float* __restrict__ C, int M, int N, int K)
{
    int id = blockIdx.x * 256 + threadIdx.x;
    if (id >= M * N) return;
    int m = id / N, n = id - m * N;
    float acc = bias ? fs(bias[n]) : 0.f;
    const float* Ap = A + (size_t)m * lda;
    for (int k = 0; k < K; k++) acc += Ap[k] * fs(B[(size_t)k * N + n]);
    C[id] = (ACT == 1) ? gelu_f(acc) : acc;
}

// bf16 MFMA GEMM: C(M,N) = act(A(M,K)@B(K,N) + bias), fp32 in/out, bf16 compute.
// M % 64 == 0 and N % 64 == 0 required (all call sites satisfy this).
template <int ACT>
__global__ __launch_bounds__(256) void k_gemm_mfma(
    const float* __restrict__ A, int lda,
    const float* __restrict__ B, int ldb,
    const float* __restrict__ bias,
    float* __restrict__ C, int ldc, int K)
{
    __shared__ u16 As[64 * 40];
    __shared__ u16 Bs[64 * 40];
    const int t = threadIdx.x;
    const int lane = t & 63, wave = t >> 6;
    const int m0 = blockIdx.y << 6, n0 = blockIdx.x << 6;
    const int wm = (wave & 1) << 5, wn = (wave >> 1) << 5;
    const int sr = t >> 2, sk = (t & 3) << 3;
    const int bn = t & 63, bw = t >> 6;
    const int frm = lane & 15, frq = lane >> 4, frk = frq << 3;
    const f32x4 z = {0.f, 0.f, 0.f, 0.f};
    f32x4 acc[2][2] = {{z, z}, {z, z}};
    for (int k0 = 0; k0 < K; k0 += 32) {
        {
            const float* p = A + (size_t)(m0 + sr) * lda + k0 + sk;
#pragma unroll
            for (int i = 0; i < 8; i++)
                As[sr * 40 + sk + i] = (k0 + sk + i < K) ? f2b(fs(p[i])) : (u16)0;
        }
#pragma unroll
        for (int kk = bw; kk < 32; kk += 4)
            Bs[bn * 40 + kk] = (k0 + kk < K) ? f2b(fs(B[(size_t)(k0 + kk) * ldb + n0 + bn])) : (u16)0;
        __syncthreads();
        bf16x8 a0 = *(const bf16x8*)&As[(wm + frm) * 40 + frk];
        bf16x8 a1 = *(const bf16x8*)&As[(wm + 16 + frm) * 40 + frk];
        bf16x8 b0 = *(const bf16x8*)&Bs[(wn + frm) * 40 + frk];
        bf16x8 b1 = *(const bf16x8*)&Bs[(wn + 16 + frm) * 40 + frk];
        acc[0][0] = __builtin_amdgcn_mfma_f32_16x16x32_bf16(a0, b0, acc[0][0], 0, 0, 0);
        acc[0][1] = __builtin_amdgcn_mfma_f32_16x16x32_bf16(a0, b1, acc[0][1], 0, 0, 0);
        acc[1][0] = __builtin_amdgcn_mfma_f32_16x16x32_bf16(a1, b0, acc[1][0], 0, 0, 0);
        acc[1][1] = __builtin_amdgcn_mfma_f32_16x16x32_bf16(a1, b1, acc[1][1], 0, 0, 0);
        __syncthreads();
    }
#pragma unroll
    for (int mi = 0; mi < 2; mi++) {
#pragma unroll
        for (int ni = 0; ni < 2; ni++) {
            int col = n0 + wn + (ni << 4) + frm;
            float bv = bias ? fs(bias[col]) : 0.f;
#pragma unroll
            for (int r = 0; r < 4; r++) {
                int row = m0 + wm + (mi << 4) + (frq << 2) + r;
                float v = acc[mi][ni][r] + bv;
                if (ACT == 1) v = gelu_f(v);
                C[(size_t)row * ldc + col] = v;
            }
        }
    }
}

// fused score-bias MLP: one block per b (192 threads); hid kept in LDS
__global__ __launch_bounds__(192) void k_mlpbias(
    const float* __restrict__ sdiff, const float* __restrict__ Wss1,
    const float* __restrict__ bss1, const float* __restrict__ Wss2,
    const float* __restrict__ bss2, float* __restrict__ bias_s)
{
    __shared__ float sdS[32 * 12];
    __shared__ float hidS[32 * 192];
    const int b = blockIdx.x;
    const int t = threadIdx.x;
    for (int i = t; i < 384; i += 192) sdS[i] = sdiff[(size_t)b * 384 + i];
    __syncthreads();
    {
        float w[12];
#pragma unroll
        for (int j = 0; j < 12; j++) w[j] = fs(Wss1[j * 192 + t]);
        float b1 = fs(bss1[t]);
        for (int k = 0; k < 32; k++) {
            float acc = b1;
#pragma unroll
            for (int j = 0; j < 12; j++) acc += sdS[k * 12 + j] * w[j];
            hidS[k * 192 + t] = gelu_f(acc);
        }
    }
    __syncthreads();
    {
        int k = t / 6, s = t - k * 6;
        float acc = fs(bss2[s]);
        for (int n = 0; n < 192; n++) acc += hidS[k * 192 + n] * fs(Wss2[n * 6 + s]);
        bias_s[(size_t)(b * 32 + k) * 6 + s] = acc;
    }
}

__global__ void k_qp(const float* __restrict__ Qh, const float* __restrict__ Wak,
                     float* __restrict__ Qp, int BCc)
{
    int id = blockIdx.x * 256 + threadIdx.x;
    if (id >= BCc * 2304) return;
    int b = id / 2304, c = id - b * 2304, h = c / 384, j = c - h * 384;
    float acc = 0.f;
    for (int d = 0; d < 64; d++)
        acc += Qh[(size_t)b * 384 + h * 64 + d] * fs(Wak[(size_t)j * 384 + h * 64 + d]);
    Qp[id] = acc;
}

__global__ void k_qkb(const float* __restrict__ Qh, const float* __restrict__ bak,
                      float* __restrict__ qkb, int BCc)
{
    int id = blockIdx.x * 256 + threadIdx.x;
    if (id >= BCc * 6) return;
    int b = id / 6, h = id - b * 6;
    float acc = 0.f;
    for (int d = 0; d < 64; d++)
        acc += Qh[(size_t)b * 384 + h * 64 + d] * fs(bak[h * 64 + d]);
    qkb[id] = acc;
}

// attention with kv computed in-block from nbr (kv global buffer eliminated)
__global__ __launch_bounds__(384) void k_attnblk(
    const float* __restrict__ nbr, const float* __restrict__ Wnp,
    const float* __restrict__ bnp, const float* __restrict__ Qp,
    const float* __restrict__ qkb, const float* __restrict__ bias_s,
    const int* __restrict__ rvalid, const float* __restrict__ anyv,
    const float* __restrict__ Wav, const float* __restrict__ bav,
    float* __restrict__ attn)
{
    __shared__ float kvs[32 * 384];   // 48 KB
    __shared__ float nbs[32 * 30];
    __shared__ float vms[6 * 384];    // 9 KB
    __shared__ float wsx[192];
    const int b = blockIdx.x;
    const int t = threadIdx.x;
    for (int i = t; i < 960; i += 384) nbs[i] = nbr[(size_t)b * 960 + i];
    __syncthreads();
    {   // kv[k][t] = gelu(sum_j nbs[k][j]*Wnp[j][t] + bnp[t]); Wnp column cached in regs
        float w[30];
#pragma unroll
        for (int j = 0; j < 30; j++) w[j] = fs(Wnp[j * 384 + t]);
        float bb = fs(bnp[t]);
        for (int k = 0; k < 32; k++) {
            float acc = bb;
#pragma unroll
            for (int j = 0; j < 30; j++) acc += nbs[k * 30 + j] * w[j];
            kvs[k * 384 + t] = gelu_f(acc);
        }
    }
    __syncthreads();
    if (t < 192) {
        int h = t >> 5, k = t & 31;
        const float* qpp = Qp + (size_t)b * 2304 + (size_t)h * 384;
        float s = 0.f;
        for (int j = 0; j < 384; j++) s += kvs[k * 384 + j] * qpp[j];
        s = (s + qkb[b * 6 + h]) * 0.125f + bias_s[(size_t)(b * 32 + k) * 6 + h];
        bool ve = (rvalid[b * 32 + k] != 0) || (anyv[b] == 0.f && k == 0);
        wsx[h * 32 + k] = ve ? s : -10000.f;
    }
    __syncthreads();
    if (t < 6) {
        float mx = -1e30f;
        for (int k = 0; k < 32; k++) mx = fmaxf(mx, wsx[t * 32 + k]);
        float sum = 0.f;
        for (int k = 0; k < 32; k++) { float e = expf(wsx[t * 32 + k] - mx); wsx[t * 32 + k] = e; sum += e; }
        float inv = 1.f / sum;
        for (int k = 0; k < 32; k++) wsx[t * 32 + k] *= inv;
    }
    __syncthreads();
    for (int i = 0; i < 6; i++) {
        int idx = i * 384 + t;
        int h = idx / 384, j = idx - h * 384;
        float acc = 0.f;
        for (int k = 0; k < 32; k++) acc += wsx[h * 32 + k] * kvs[k * 384 + j];
        vms[idx] = acc;
    }
    __syncthreads();
    {
        int c = t, h = c >> 6;
        float acc = fs(bav[c]);
        const float* vp = vms + h * 384;
        for (int j = 0; j < 384; j++) acc += vp[j] * fs(Wav[(size_t)j * 384 + c]);
        attn[(size_t)b * 384 + c] = acc;
    }
}

__global__ void k_ctxout(const float* __restrict__ ctx, const float* __restrict__ anyv,
                         const float* __restrict__ fctx, float* __restrict__ out, int BCc)
{
    int id = blockIdx.x * 256 + threadIdx.x;
    if (id >= BCc * 384) return;
    int b = id / 384, c = id - b * 384;
    float v = (anyv[b] > 0.f) ? ctx[id] : fs(fctx[c]);
    out[id] = fin(v);
}

__global__ void k_xtc(const float* __restrict__ tq, const int* __restrict__ qcode,
                      const float* __restrict__ Etr, const float* __restrict__ gst,
                      float* __restrict__ X, int BCc)
{
    int id = blockIdx.x * 256 + threadIdx.x;
    if (id >= BCc * 420) return;
    int b = id / 420, c = id - b * 420;
    float v;
    if (c < 384) v = tq[(size_t)b * 384 + c];
    else if (c < 416) v = fs(Etr[min(max(qcode[b], 0), 20) * 32 + (c - 384)]);
    else v = gst[(size_t)b * 4 + (c - 416)];
    X[id] = v;
}

__global__ void k_transfer(const float* __restrict__ nbr, const int* __restrict__ rsmask,
                           const int* __restrict__ rvalid, const float* __restrict__ swb,
                           const float* __restrict__ anyv, const float* __restrict__ sscale,
                           const float* __restrict__ fshift, float* __restrict__ out, int BCc)
{
    int id = blockIdx.x * 256 + threadIdx.x;
    if (id >= BCc * 6) return;
    int b = id / 6, s = id - b * 6;
    float res;
    if (anyv[b] <= 0.f) {
        res = fs(fshift[s]);
    } else {
        float wb = swb[b * 6 + s] * 0.1f;
        float mx = -1e30f;
        for (int k = 0; k < 32; k++) {
            int gk = b * 32 + k;
            bool m = (rvalid[gk] != 0) && (rsmask[gk * 6 + s] != 0);
            float wv = m ? (nbr[(size_t)gk * 30 + 28] + nbr[(size_t)gk * 30 + 29] * 0.5f + wb)
                         : -10000.f;
            mx = fmaxf(mx, wv);
        }
        float num = 0.f, den = 0.f;
        for (int k = 0; k < 32; k++) {
            int gk = b * 32 + k;
            bool m = (rvalid[gk] != 0) && (rsmask[gk * 6 + s] != 0);
            float wv = m ? (nbr[(size_t)gk * 30 + 28] + nbr[(size_t)gk * 30 + 29] * 0.5f + wb)
                         : -10000.f;
            float e = expf(wv - mx);
            num += e * nbr[(size_t)gk * 30 + s];
            den += e;
        }
        res = (num / den) * fs(sscale[s]);
    }
    out[id] = fin(res);
}

__global__ void k_trust(const float* __restrict__ tcp, const float* __restrict__ pst,
                        const float* __restrict__ Wtp1, const float* __restrict__ Wtp2,
                        const float* __restrict__ btp2, float* __restrict__ out, int BCc)
{
    int id = blockIdx.x * 256 + threadIdx.x;
    if (id >= BCc * 6) return;
    int b = id / 6, s = id - b * 6;
    const float* ps = pst + (size_t)b * 24 + s * 4;
    float acc = 0.f;
    for (int j = 0; j < 192; j++) {
        float pre = tcp[(size_t)b * 192 + j];
        pre += ps[0] * fs(Wtp1[(size_t)384 * 192 + j]);
        pre += ps[1] * fs(Wtp1[(size_t)385 * 192 + j]);
        pre += ps[2] * fs(Wtp1[(size_t)386 * 192 + j]);
        pre += ps[3] * fs(Wtp1[(size_t)387 * 192 + j]);
        acc += gelu_f(pre) * fs(Wtp2[j]);
    }
    float t = 1.f / (1.f + expf(-(acc + fs(btp2[0]))));
    out[id] = fin(t);
}

#define L1(total) <<<((total) + 255) / 256, 256, 0, stream>>>

extern "C" void kernel_launch(void* const* d_in, const int* in_sizes, int n_in,
                              void* d_out, int out_size, void* d_ws, size_t ws_size,
                              hipStream_t stream)
{
    float* out = (float*)d_out;

    static const int EXP[45] = {
        2097152, 4096, 24576, 24576, 786432, 786432, 131072, 131072, 131072, 126,
        196608, 384, 336, 11520, 384, 147456, 384, 147456, 384, 147456, 384,
        2304, 192, 1152, 6, 147456, 384, 147456, 384, 147456, 384, 2304, 6,
        672, 196608, 384, 161280, 384, 74496, 192, 192, 1, 6, 6, 384
    };
    if (n_in != 45) {
        fill_kernel L1(out_size)(out, out_size, 580.0f);
        return;
    }
    for (int i = 0; i < 45; i++) {
        if (in_sizes[i] != EXP[i]) {
            fill_kernel L1(out_size)(out, out_size, 600.0f + 4.0f * i);
            return;
        }
    }

    const float* i_qe    = (const float*)d_in[0];
    const int*   i_qcode = (const int*)d_in[1];
    const float* i_qobs  = (const float*)d_in[2];
    const float* i_qmask = (const float*)d_in[3];
    const float* i_rshift= (const float*)d_in[4];
    const int*   i_rsmask= (const int*)d_in[5];
    const int*   i_rcodes= (const int*)d_in[6];
    const float* i_rdist = (const float*)d_in[7];
    const int*   i_rvalid= (const int*)d_in[8];
    const float* i_rc    = (const float*)d_in[9];
    const float* i_Wqp   = (const float*)d_in[10];
    const float* i_bqp   = (const float*)d_in[11];
    const float* i_Eres  = (const float*)d_in[12];
    const float* i_Wnp   = (const float*)d_in[13];
    const float* i_bnp   = (const float*)d_in[14];
    const float* i_Waq   = (const float*)d_in[15];
    const float* i_baq   = (const float*)d_in[16];
    const float* i_Wak   = (const float*)d_in[17];
    const float* i_bak   = (const float*)d_in[18];
    const float* i_Wav   = (const float*)d_in[19];
    const float* i_bav   = (const float*)d_in[20];
    const float* i_Wss1  = (const float*)d_in[21];
    const float* i_bss1  = (const float*)d_in[22];
    const float* i_Wss2  = (const float*)d_in[23];
    const float* i_bss2  = (const float*)d_in[24];
    const float* i_Wcp1  = (const float*)d_in[25];
    const float* i_bcp1  = (const float*)d_in[26];
    const float* i_Wcp2  = (const float*)d_in[27];
    const float* i_bcp2  = (const float*)d_in[28];
    const float* i_Wsw1  = (const float*)d_in[29];
    const float* i_bsw1  = (const float*)d_in[30];
    const float* i_Wsw2  = (const float*)d_in[31];
    const float* i_bsw2  = (const float*)d_in[32];
    const float* i_Etr   = (const float*)d_in[33];
    const float* i_Wtq   = (const float*)d_in[34];
    const float* i_btq   = (const float*)d_in[35];
    const float* i_Wtc   = (const float*)d_in[36];
    const float* i_btc   = (const float*)d_in[37];
    const float* i_Wtp1  = (const float*)d_in[38];
    const float* i_btp1  = (const float*)d_in[39];
    const float* i_Wtp2  = (const float*)d_in[40];
    const float* i_btp2  = (const float*)d_in[41];
    const float* i_sscale= (const float*)d_in[42];
    const float* i_fshift= (const float*)d_in[43];
    const float* i_fctx  = (const float*)d_in[44];

    // ws-adaptive chunk (kv/hid buffers eliminated -> BC=4096 fits in ~124 MB)
    auto layoutBytes = [](int bc) -> size_t {
        size_t nb = (size_t)bc * 32, off = 0;
        auto a = [&](size_t nf) { off = (off + nf * 4 + 255) & ~(size_t)255; };
        a(nb * 30); a(nb * 12); a(nb * 6);
        a((size_t)bc * 384); a((size_t)bc * 384); a((size_t)bc * 384); a((size_t)bc * 384);
        a((size_t)bc * 384); a((size_t)bc * 384); a((size_t)bc * 384); a((size_t)bc * 384);
        a((size_t)bc * 192); a((size_t)bc * 420); a((size_t)bc * 2304);
        a((size_t)bc * 6); a((size_t)bc * 6); a((size_t)bc * 24); a((size_t)bc * 4); a(bc);
        return off;
    };
    const int cand[7] = {4096, 2048, 1024, 512, 256, 128, 64};
    int BCc = 64;
    for (int i = 0; i < 7; i++) {
        if (layoutBytes(cand[i]) <= ws_size) { BCc = cand[i]; break; }
    }
    const int NBc = BCc * 32;

    char* wsb = (char*)d_ws;
    size_t off = 0;
    auto alloc = [&](size_t nfloats) -> float* {
        float* p = (float*)(wsb + off);
        off = (off + nfloats * 4 + 255) & ~(size_t)255;
        return p;
    };
    float* nbr   = alloc((size_t)NBc * 30);
    float* sdiff = alloc((size_t)NBc * 12);
    float* bias_s= alloc((size_t)NBc * 6);
    float* qf    = alloc((size_t)BCc * 384);
    float* tqf   = alloc((size_t)BCc * 384);
    float* Qhf   = alloc((size_t)BCc * 384);
    float* attnf = alloc((size_t)BCc * 384);
    float* h1f   = alloc((size_t)BCc * 384);
    float* s1f   = alloc((size_t)BCc * 384);
    float* ctxf  = alloc((size_t)BCc * 384);
    float* tcf   = alloc((size_t)BCc * 384);
    float* tcpf  = alloc((size_t)BCc * 192);
    float* Xf    = alloc((size_t)BCc * 420);
    float* Qpf   = alloc((size_t)BCc * 2304);
    float* swbf  = alloc((size_t)BCc * 6);
    float* qkbf  = alloc((size_t)BCc * 6);
    float* pstf  = alloc((size_t)BCc * 24);
    float* gstf  = alloc((size_t)BCc * 4);
    float* anyf  = alloc((size_t)BCc);

    if (off > ws_size) {
        fill_kernel L1(out_size)(out, out_size, 1000.0f);
        return;
    }

    for (int c = 0; c < 4096 / BCc; c++) {
        const size_t B0 = (size_t)c * BCc;
        const dim3 g6(6, BCc / 64), g3(3, BCc / 64);
        k_prep L1(NBc)(i_qobs + B0 * 6, i_qmask + B0 * 6, i_rshift + B0 * 192,
                       i_rsmask + B0 * 192, i_qcode + B0, i_rcodes + B0 * 32,
                       i_rdist + B0 * 32, i_rc, i_Eres, nbr, sdiff, NBc);
        k_stats L1(BCc)(nbr, i_rvalid + B0 * 32, pstf, gstf, anyf, BCc);
        k_mlpbias<<<BCc, 192, 0, stream>>>(sdiff, i_Wss1, i_bss1, i_Wss2, i_bss2, bias_s);
        k_gemm_mfma<1><<<g6, 256, 0, stream>>>(i_qe + B0 * 512, 512, i_Wqp, 384, i_bqp, qf, 384, 512);
        k_gemm_mfma<1><<<g6, 256, 0, stream>>>(i_qe + B0 * 512, 512, i_Wtq, 384, i_btq, tqf, 384, 512);
        k_gemm_mfma<0><<<g6, 256, 0, stream>>>(qf, 384, i_Waq, 384, i_baq, Qhf, 384, 384);
        k_qp L1(BCc * 2304)(Qhf, i_Wak, Qpf, BCc);
        k_qkb L1(BCc * 6)(Qhf, i_bak, qkbf, BCc);
        k_attnblk<<<BCc, 384, 0, stream>>>(nbr, i_Wnp, i_bnp, Qpf, qkbf, bias_s,
                                           i_rvalid + B0 * 32, anyf, i_Wav, i_bav, attnf);
        k_gemm_mfma<1><<<g6, 256, 0, stream>>>(attnf, 384, i_Wcp1, 384, i_bcp1, h1f, 384, 384);
        k_gemm_mfma<0><<<g6, 256, 0, stream>>>(h1f, 384, i_Wcp2, 384, i_bcp2, ctxf, 384, 384);
        k_gemm_mfma<1><<<g6, 256, 0, stream>>>(attnf, 384, i_Wsw1, 384, i_bsw1, s1f, 384, 384);
        k_gemm<0> L1(BCc * 6)(s1f, 384, i_Wsw2, i_bsw2, swbf, BCc, 6, 384);
        k_ctxout L1(BCc * 384)(ctxf, anyf, i_fctx, out + B0 * 384, BCc);
        k_xtc L1(BCc * 420)(tqf, i_qcode + B0, i_Etr, gstf, Xf, BCc);
        k_gemm_mfma<1><<<g6, 256, 0, stream>>>(Xf, 420, i_Wtc, 384, i_btc, tcf, 384, 420);
        k_gemm_mfma<0><<<g3, 256, 0, stream>>>(tcf, 384, i_Wtp1, 192, i_btp1, tcpf, 192, 384);
        k_trust L1(BCc * 6)(tcpf, pstf, i_Wtp1, i_Wtp2, i_btp2,
                            out + (size_t)4096 * 390 + B0 * 6, BCc);
        k_transfer L1(BCc * 6)(nbr, i_rsmask + B0 * 192, i_rvalid + B0 * 32, swbf, anyf,
                               i_sscale, i_fshift, out + (size_t)4096 * 384 + B0 * 6, BCc);
    }
}